// Round 2
// baseline (209.514 us; speedup 1.0000x reference)
//
#include <hip/hip_runtime.h>
#include <math.h>

#define N_NODES 10000
#define N_EDGES 320000
#define CAP 128   // max in-degree bucket capacity (mean 32, +17 sigma)

__device__ __forceinline__ float silu_f(float x) {
    return x / (1.0f + __expf(-x));
}

// ---------------- kernel 0: transpose fc weights for contiguous scalar loads ----
__global__ __launch_bounds__(256) void transpose_kernel(
    const float* __restrict__ fw1, const float* __restrict__ fw2,
    float* __restrict__ w1T, float* __restrict__ w2T)
{
    int t = blockIdx.x * 256 + threadIdx.x;
    if (t < 4096) {
        int i = t / 64, j = t % 64;          // fw2 is (64,64): [i][j]
        w2T[j * 64 + i] = fw2[t];
    }
    if (t < 640) {
        int i = t / 64, j = t % 64;          // fw1 is (10,64): [i][j]
        w1T[j * 10 + i] = fw1[t];
    }
}

// ---------------- kernel 1: per-node Ai = mlp(atom_emb[A]) ----------------------
__global__ __launch_bounds__(256) void node_ai_kernel(
    const float* __restrict__ atom_emb, const int* __restrict__ A,
    const float* __restrict__ w1, const float* __restrict__ b1,
    const float* __restrict__ w2, const float* __restrict__ b2,
    float* __restrict__ Ai)
{
    int n = blockIdx.x * blockDim.x + threadIdx.x;
    if (n >= N_NODES) return;
    int a = A[n];
    float emb[16];
    #pragma unroll
    for (int i = 0; i < 16; ++i) emb[i] = atom_emb[a * 16 + i];
    float acc[8];
    #pragma unroll
    for (int o = 0; o < 8; ++o) acc[o] = b2[o];
    #pragma unroll 4
    for (int j = 0; j < 64; ++j) {
        float s0 = b1[j], s1 = 0.f;
        #pragma unroll
        for (int i = 0; i < 16; i += 2) {
            s0 += emb[i]     * w1[i * 64 + j];
            s1 += emb[i + 1] * w1[(i + 1) * 64 + j];
        }
        float h = silu_f(s0 + s1);
        #pragma unroll
        for (int o = 0; o < 8; ++o) acc[o] += h * w2[j * 8 + o];
    }
    #pragma unroll
    for (int o = 0; o < 8; ++o) Ai[n * 8 + o] = acc[o];
}

// ---------------- kernel 2: per-edge radial MLP -> q[e] + bucket insert ---------
// q[e] = (gate0, gate3*Y1[3], gate9*Y2[5]) padded to 12 floats.
// One int atomic per edge (bucket slot); no f32 atomics anywhere.
__global__ __launch_bounds__(256) void edge_kernel(
    const float* __restrict__ pos, const float* __restrict__ edge_shifts,
    const float* __restrict__ cell, const int* __restrict__ batch,
    const int* __restrict__ edge_src, const int* __restrict__ edge_dst,
    const float* __restrict__ w1T, const float* __restrict__ fb1,
    const float* __restrict__ w2T, const float* __restrict__ fb2,
    const float* __restrict__ fw3, const float* __restrict__ fb3,
    float* __restrict__ Q, int* __restrict__ deg, int* __restrict__ elist)
{
    int e = blockIdx.x * blockDim.x + threadIdx.x;
    if (e >= N_EDGES) return;

    int src = edge_src[e], dst = edge_dst[e];
    int b = batch[src];

    float s0 = edge_shifts[e * 3 + 0];
    float s1 = edge_shifts[e * 3 + 1];
    float s2 = edge_shifts[e * 3 + 2];
    const float* Cb = cell + b * 9;
    float shx = s0 * Cb[0] + s1 * Cb[3] + s2 * Cb[6];
    float shy = s0 * Cb[1] + s1 * Cb[4] + s2 * Cb[7];
    float shz = s0 * Cb[2] + s1 * Cb[5] + s2 * Cb[8];

    float vx = pos[dst * 3 + 0] - pos[src * 3 + 0] + shx;
    float vy = pos[dst * 3 + 1] - pos[src * 3 + 1] + shy;
    float vz = pos[dst * 3 + 2] - pos[src * 3 + 2] + shz;

    float r = sqrtf(vx * vx + vy * vy + vz * vz);
    float rinv = 1.0f / fmaxf(r, 1e-8f);
    float nx = vx * rinv, ny = vy * rinv, nz = vz * rinv;

    // spherical harmonics (l=1,2)
    const float SQ3 = 1.7320508075688772f;
    const float SQ15 = 3.872983346207417f;
    const float SQ5H = 1.1180339887498949f;   // sqrt(5)/2
    float y1x = SQ3 * nx, y1y = SQ3 * ny, y1z = SQ3 * nz;
    float y20 = SQ15 * nx * ny;
    float y21 = SQ15 * ny * nz;
    float y22 = SQ5H * (3.0f * nz * nz - 1.0f);
    float y23 = SQ15 * nx * nz;
    float y24 = 0.5f * SQ15 * (nx * nx - ny * ny);

    // radial basis: d_i = r*2.2 - (i+1); rb = exp(-d^2)/1.12*sqrt(10)
    float rb[10];
    float t = r * 2.2f;
    #pragma unroll
    for (int i = 0; i < 10; ++i) {
        float d = t - (float)(i + 1);
        rb[i] = __expf(-d * d) * 2.8234622f;
    }

    // fc1
    float g1[64];
    #pragma unroll
    for (int j = 0; j < 64; ++j) {
        float a0 = fb1[j], a1 = 0.f;
        #pragma unroll
        for (int i = 0; i < 10; i += 2) {
            a0 += rb[i]     * w1T[j * 10 + i];
            a1 += rb[i + 1] * w1T[j * 10 + i + 1];
        }
        g1[j] = silu_f(a0 + a1);
    }

    // fc2 + fc3 (only gate columns 0,3,9 survive the l2==0 path filter)
    float gate0 = fb3[0], gate3 = fb3[3], gate9 = fb3[9];
    for (int j = 0; j < 64; ++j) {
        float a0 = fb2[j], a1 = 0.f, a2 = 0.f, a3 = 0.f;
        #pragma unroll
        for (int i = 0; i < 64; i += 4) {
            a0 += g1[i]     * w2T[j * 64 + i];
            a1 += g1[i + 1] * w2T[j * 64 + i + 1];
            a2 += g1[i + 2] * w2T[j * 64 + i + 2];
            a3 += g1[i + 3] * w2T[j * 64 + i + 3];
        }
        float h = silu_f((a0 + a1) + (a2 + a3));
        gate0 += h * fw3[j * 15 + 0];
        gate3 += h * fw3[j * 15 + 3];
        gate9 += h * fw3[j * 15 + 9];
    }

    float* Qe = Q + (size_t)e * 12;
    float4 q0 = make_float4(gate0, gate3 * y1x, gate3 * y1y, gate3 * y1z);
    float4 q1 = make_float4(gate9 * y20, gate9 * y21, gate9 * y22, gate9 * y23);
    float4 q2 = make_float4(gate9 * y24, 0.f, 0.f, 0.f);
    *(float4*)(Qe + 0) = q0;
    *(float4*)(Qe + 4) = q1;
    *(float4*)(Qe + 8) = q2;

    int pos_ = atomicAdd(&deg[dst], 1);
    if (pos_ < CAP) elist[dst * CAP + pos_] = e;
}

// ---------------- kernel 3: per-node gather M[n][u][9] (no atomics) -------------
// One wave per node; lane = (slot 0..7) * 8 + (u 0..7).
__global__ __launch_bounds__(256) void gather_kernel(
    const int* __restrict__ deg, const int* __restrict__ elist,
    const int* __restrict__ edge_src, const float* __restrict__ Q,
    const float* __restrict__ Ai, float* __restrict__ M)
{
    int tid = threadIdx.x;
    int lane = tid & 63;
    int n = blockIdx.x * 4 + (tid >> 6);
    int u = lane & 7;
    int slot = lane >> 3;

    int d = deg[n];
    if (d > CAP) d = CAP;

    float acc[9];
    #pragma unroll
    for (int k = 0; k < 9; ++k) acc[k] = 0.f;

    const int* el = elist + n * CAP;
    for (int i = slot; i < d; i += 8) {
        int e = el[i];
        int src = edge_src[e];
        float au = Ai[src * 8 + u];
        const float* q = Q + (size_t)e * 12;
        float4 qa = *(const float4*)(q + 0);
        float4 qb = *(const float4*)(q + 4);
        float  qc = q[8];
        acc[0] += qa.x * au; acc[1] += qa.y * au; acc[2] += qa.z * au;
        acc[3] += qa.w * au; acc[4] += qb.x * au; acc[5] += qb.y * au;
        acc[6] += qb.z * au; acc[7] += qb.w * au; acc[8] += qc   * au;
    }

    #pragma unroll
    for (int m = 8; m < 64; m <<= 1) {
        #pragma unroll
        for (int k = 0; k < 9; ++k) acc[k] += __shfl_xor(acc[k], m, 64);
    }

    if (slot == 0) {
        float* Mn = M + n * 72 + u * 9;
        #pragma unroll
        for (int k = 0; k < 9; ++k) Mn[k] = acc[k];
    }
}

// ---------------- kernel 4: per-node contraction with tp_w and output ----------
// M layout: [n][u][9] with k: 0 -> l0, 1..3 -> l1, 4..8 -> l2.
__global__ __launch_bounds__(256) void node_out_kernel(
    const float* __restrict__ Ai, const float* __restrict__ M,
    const int* __restrict__ deg, const float* __restrict__ tp_w,
    float* __restrict__ out)
{
    __shared__ float sM[8][72];
    __shared__ float sA[8][8];
    int t = threadIdx.x;
    int nodeBase = blockIdx.x * 8;

    for (int i = t; i < 576; i += 256) {
        int ln = i / 72;
        sM[ln][i % 72] = M[(nodeBase + ln) * 72 + (i % 72)];
    }
    if (t < 64) sA[t / 8][t % 8] = Ai[nodeBase * 8 + t];
    __syncthreads();

    int ln = t / 32, w = t % 32;
    int n = nodeBase + ln;
    if (n >= N_NODES) return;

    float a[8];
    #pragma unroll
    for (int v = 0; v < 8; ++v) a[v] = sA[ln][v];
    float inv = 1.0f / fmaxf((float)deg[n], 1.0f);

    const float* W0 = tp_w + 0 * 2048;   // path (0,0,0)
    const float* W3 = tp_w + 3 * 2048;   // path (1,0,1)
    const float* W9 = tp_w + 9 * 2048;   // path (2,0,2)

    // l=0 block (32 floats at offset 0)
    {
        float o0 = 0.f;
        #pragma unroll
        for (int u = 0; u < 8; ++u) {
            float c = 0.f;
            #pragma unroll
            for (int v = 0; v < 8; ++v) c += a[v] * W0[(u * 8 + v) * 32 + w];
            o0 += sM[ln][u * 9] * c;
        }
        out[n * 288 + w] = o0 * inv;
    }
    // l=1 block (96 floats at offset 32), layout [w][k], k<3
    {
        float o1[3] = {0.f, 0.f, 0.f};
        #pragma unroll
        for (int u = 0; u < 8; ++u) {
            float c = 0.f;
            #pragma unroll
            for (int v = 0; v < 8; ++v) c += a[v] * W3[(u * 8 + v) * 32 + w];
            #pragma unroll
            for (int k = 0; k < 3; ++k) o1[k] += sM[ln][u * 9 + 1 + k] * c;
        }
        #pragma unroll
        for (int k = 0; k < 3; ++k) out[n * 288 + 32 + w * 3 + k] = o1[k] * inv;
    }
    // l=2 block (160 floats at offset 128), layout [w][k], k<5
    {
        float o2[5] = {0.f, 0.f, 0.f, 0.f, 0.f};
        #pragma unroll
        for (int u = 0; u < 8; ++u) {
            float c = 0.f;
            #pragma unroll
            for (int v = 0; v < 8; ++v) c += a[v] * W9[(u * 8 + v) * 32 + w];
            #pragma unroll
            for (int k = 0; k < 5; ++k) o2[k] += sM[ln][u * 9 + 4 + k] * c;
        }
        #pragma unroll
        for (int k = 0; k < 5; ++k) out[n * 288 + 128 + w * 5 + k] = o2[k] * inv;
    }
}

// ---------------- launch ---------------------------------------------------------
extern "C" void kernel_launch(void* const* d_in, const int* in_sizes, int n_in,
                              void* d_out, int out_size, void* d_ws, size_t ws_size,
                              hipStream_t stream) {
    const float* pos         = (const float*)d_in[0];
    const float* edge_shifts = (const float*)d_in[1];
    const float* cell        = (const float*)d_in[2];
    const float* atom_emb    = (const float*)d_in[3];
    const float* mlp_w1      = (const float*)d_in[4];
    const float* mlp_b1      = (const float*)d_in[5];
    const float* mlp_w2      = (const float*)d_in[6];
    const float* mlp_b2      = (const float*)d_in[7];
    const float* fc_w1       = (const float*)d_in[8];
    const float* fc_b1       = (const float*)d_in[9];
    const float* fc_w2       = (const float*)d_in[10];
    const float* fc_b2       = (const float*)d_in[11];
    const float* fc_w3       = (const float*)d_in[12];
    const float* fc_b3       = (const float*)d_in[13];
    const float* tp_w        = (const float*)d_in[14];
    const int*   A           = (const int*)d_in[15];
    const int*   batch       = (const int*)d_in[16];
    const int*   edge_src    = (const int*)d_in[17];
    const int*   edge_dst    = (const int*)d_in[18];
    float* out = (float*)d_out;

    // workspace layout (all 16B aligned):
    // floats: Q[320000*12] | Ai[80000] | M[720000] | w2T[4096] | w1T[640]
    // ints:   deg[10000] | elist[10000*128]
    float* Q   = (float*)d_ws;
    float* Ai  = Q + (size_t)N_EDGES * 12;
    float* M   = Ai + N_NODES * 8;
    float* w2T = M + N_NODES * 72;
    float* w1T = w2T + 64 * 64;
    int*   deg   = (int*)(w1T + 640);
    int*   elist = deg + N_NODES;
    // total: ~23.8 MB

    hipMemsetAsync(deg, 0, N_NODES * sizeof(int), stream);

    transpose_kernel<<<16, 256, 0, stream>>>(fc_w1, fc_w2, w1T, w2T);

    node_ai_kernel<<<(N_NODES + 255) / 256, 256, 0, stream>>>(
        atom_emb, A, mlp_w1, mlp_b1, mlp_w2, mlp_b2, Ai);

    edge_kernel<<<N_EDGES / 256, 256, 0, stream>>>(
        pos, edge_shifts, cell, batch, edge_src, edge_dst,
        w1T, fc_b1, w2T, fc_b2, fc_w3, fc_b3, Q, deg, elist);

    gather_kernel<<<N_NODES / 4, 256, 0, stream>>>(
        deg, elist, edge_src, Q, Ai, M);

    node_out_kernel<<<N_NODES / 8, 256, 0, stream>>>(Ai, M, deg, tp_w, out);
}

// Round 4
// 205.178 us; speedup vs baseline: 1.0211x; 1.0211x over previous
//
#include <hip/hip_runtime.h>
#include <math.h>

#define N_NODES 10000
#define N_EDGES 320000
#define CAP 128   // max in-degree bucket capacity (mean 32, +17 sigma)

__device__ __forceinline__ float silu_f(float x) {
    return x / (1.0f + __expf(-x));
}

// ---------------- kernel 1: node Ai MLP (blocks 0..39) + weight transpose (last block)
__global__ __launch_bounds__(256) void node_ai_kernel(
    const float* __restrict__ atom_emb, const int* __restrict__ A,
    const float* __restrict__ w1, const float* __restrict__ b1,
    const float* __restrict__ w2, const float* __restrict__ b2,
    const float* __restrict__ fw1, const float* __restrict__ fw2,
    float* __restrict__ Ai, float* __restrict__ w1T, float* __restrict__ w2T)
{
    if (blockIdx.x == gridDim.x - 1) {
        // transpose fc weights for contiguous wave-uniform (scalar) loads
        for (int t = threadIdx.x; t < 4096; t += 256) {
            int i = t / 64, j = t % 64;          // fw2 is (64,64): [i][j]
            w2T[j * 64 + i] = fw2[t];
        }
        for (int t = threadIdx.x; t < 640; t += 256) {
            int i = t / 64, j = t % 64;          // fw1 is (10,64): [i][j]
            w1T[j * 10 + i] = fw1[t];
        }
        return;
    }
    int n = blockIdx.x * blockDim.x + threadIdx.x;
    if (n >= N_NODES) return;
    int a = A[n];
    float emb[16];
    #pragma unroll
    for (int i = 0; i < 16; ++i) emb[i] = atom_emb[a * 16 + i];
    float acc[8];
    #pragma unroll
    for (int o = 0; o < 8; ++o) acc[o] = b2[o];
    #pragma unroll 4
    for (int j = 0; j < 64; ++j) {
        float s0 = b1[j], s1 = 0.f;
        #pragma unroll
        for (int i = 0; i < 16; i += 2) {
            s0 += emb[i]     * w1[i * 64 + j];
            s1 += emb[i + 1] * w1[(i + 1) * 64 + j];
        }
        float h = silu_f(s0 + s1);
        #pragma unroll
        for (int o = 0; o < 8; ++o) acc[o] += h * w2[j * 8 + o];
    }
    #pragma unroll
    for (int o = 0; o < 8; ++o) Ai[n * 8 + o] = acc[o];
}

// ---------------- kernel 2: per-edge radial MLP -> q[e] + bucket insert ---------
// q[e] = (gate0, gate3*Y1[3], gate9*Y2[5]) padded to 12 floats.
// launch_bounds(256,2): VGPR cap 256 so g1[64] stays in registers (r2: default
// heuristic capped at 48 VGPR -> ~15MB scratch spills, 78us), while still
// guaranteeing >=2 waves/SIMD (8 waves/CU) for latency hiding.
__global__ __launch_bounds__(256, 2) void edge_kernel(
    const float* __restrict__ pos, const float* __restrict__ edge_shifts,
    const float* __restrict__ cell, const int* __restrict__ batch,
    const int* __restrict__ edge_src, const int* __restrict__ edge_dst,
    const float* __restrict__ w1T, const float* __restrict__ fb1,
    const float* __restrict__ w2T, const float* __restrict__ fb2,
    const float* __restrict__ fw3, const float* __restrict__ fb3,
    float* __restrict__ Q, int* __restrict__ deg, int* __restrict__ elist)
{
    int e = blockIdx.x * blockDim.x + threadIdx.x;
    if (e >= N_EDGES) return;

    int src = edge_src[e], dst = edge_dst[e];
    int b = batch[src];

    float s0 = edge_shifts[e * 3 + 0];
    float s1 = edge_shifts[e * 3 + 1];
    float s2 = edge_shifts[e * 3 + 2];
    const float* Cb = cell + b * 9;
    float shx = s0 * Cb[0] + s1 * Cb[3] + s2 * Cb[6];
    float shy = s0 * Cb[1] + s1 * Cb[4] + s2 * Cb[7];
    float shz = s0 * Cb[2] + s1 * Cb[5] + s2 * Cb[8];

    float vx = pos[dst * 3 + 0] - pos[src * 3 + 0] + shx;
    float vy = pos[dst * 3 + 1] - pos[src * 3 + 1] + shy;
    float vz = pos[dst * 3 + 2] - pos[src * 3 + 2] + shz;

    float r = sqrtf(vx * vx + vy * vy + vz * vz);
    float rinv = 1.0f / fmaxf(r, 1e-8f);
    float nx = vx * rinv, ny = vy * rinv, nz = vz * rinv;

    // spherical harmonics (l=1,2)
    const float SQ3 = 1.7320508075688772f;
    const float SQ15 = 3.872983346207417f;
    const float SQ5H = 1.1180339887498949f;   // sqrt(5)/2
    float y1x = SQ3 * nx, y1y = SQ3 * ny, y1z = SQ3 * nz;
    float y20 = SQ15 * nx * ny;
    float y21 = SQ15 * ny * nz;
    float y22 = SQ5H * (3.0f * nz * nz - 1.0f);
    float y23 = SQ15 * nx * nz;
    float y24 = 0.5f * SQ15 * (nx * nx - ny * ny);

    // radial basis: d_i = r*2.2 - (i+1); rb = exp(-d^2)/1.12*sqrt(10)
    float rb[10];
    float t = r * 2.2f;
    #pragma unroll
    for (int i = 0; i < 10; ++i) {
        float d = t - (float)(i + 1);
        rb[i] = __expf(-d * d) * 2.8234622f;
    }

    // fc1
    float g1[64];
    #pragma unroll
    for (int j = 0; j < 64; ++j) {
        float a0 = fb1[j], a1 = 0.f;
        #pragma unroll
        for (int i = 0; i < 10; i += 2) {
            a0 += rb[i]     * w1T[j * 10 + i];
            a1 += rb[i + 1] * w1T[j * 10 + i + 1];
        }
        g1[j] = silu_f(a0 + a1);
    }

    // fc2 + fc3 (only gate columns 0,3,9 survive the l2==0 path filter)
    float gate0 = fb3[0], gate3 = fb3[3], gate9 = fb3[9];
    for (int j = 0; j < 64; ++j) {
        float a0 = fb2[j], a1 = 0.f, a2 = 0.f, a3 = 0.f;
        #pragma unroll
        for (int i = 0; i < 64; i += 4) {
            a0 += g1[i]     * w2T[j * 64 + i];
            a1 += g1[i + 1] * w2T[j * 64 + i + 1];
            a2 += g1[i + 2] * w2T[j * 64 + i + 2];
            a3 += g1[i + 3] * w2T[j * 64 + i + 3];
        }
        float h = silu_f((a0 + a1) + (a2 + a3));
        gate0 += h * fw3[j * 15 + 0];
        gate3 += h * fw3[j * 15 + 3];
        gate9 += h * fw3[j * 15 + 9];
    }

    float* Qe = Q + (size_t)e * 12;
    float4 q0 = make_float4(gate0, gate3 * y1x, gate3 * y1y, gate3 * y1z);
    float4 q1 = make_float4(gate9 * y20, gate9 * y21, gate9 * y22, gate9 * y23);
    float4 q2 = make_float4(gate9 * y24, 0.f, 0.f, 0.f);
    *(float4*)(Qe + 0) = q0;
    *(float4*)(Qe + 4) = q1;
    *(float4*)(Qe + 8) = q2;

    int pos_ = atomicAdd(&deg[dst], 1);
    if (pos_ < CAP) elist[dst * CAP + pos_] = e;
}

// ---------------- kernel 3: fused gather + tp_w contraction + output ------------
// Block = 256 threads = 4 waves = 4 nodes.
// Phase 1: wave wv gathers M[n][u][9] (lane = slot*8+u, shfl reduce over slots).
// Phase 2: 128 threads contract with tp_w and write out[n][288].
__global__ __launch_bounds__(256) void gather_out_kernel(
    const int* __restrict__ deg, const int* __restrict__ elist,
    const int* __restrict__ edge_src, const float* __restrict__ Q,
    const float* __restrict__ Ai, const float* __restrict__ tp_w,
    float* __restrict__ out)
{
    __shared__ float sM[4][72];
    __shared__ float sA[4][8];
    int tid = threadIdx.x;
    int lane = tid & 63;
    int wv = tid >> 6;
    int nodeBase = blockIdx.x * 4;
    int n1 = nodeBase + wv;
    int u1 = lane & 7;
    int slot = lane >> 3;

    int d = deg[n1];
    int dc = d > CAP ? CAP : d;

    float acc[9];
    #pragma unroll
    for (int k = 0; k < 9; ++k) acc[k] = 0.f;

    const int* el = elist + n1 * CAP;
    for (int i = slot; i < dc; i += 8) {
        int e = el[i];
        int src = edge_src[e];
        float au = Ai[src * 8 + u1];
        const float* q = Q + (size_t)e * 12;
        float4 qa = *(const float4*)(q + 0);
        float4 qb = *(const float4*)(q + 4);
        float  qc = q[8];
        acc[0] += qa.x * au; acc[1] += qa.y * au; acc[2] += qa.z * au;
        acc[3] += qa.w * au; acc[4] += qb.x * au; acc[5] += qb.y * au;
        acc[6] += qb.z * au; acc[7] += qb.w * au; acc[8] += qc   * au;
    }

    #pragma unroll
    for (int m = 8; m < 64; m <<= 1) {
        #pragma unroll
        for (int k = 0; k < 9; ++k) acc[k] += __shfl_xor(acc[k], m, 64);
    }

    if (slot == 0) {
        #pragma unroll
        for (int k = 0; k < 9; ++k) sM[wv][u1 * 9 + k] = acc[k];
    }
    if (tid < 32) sA[tid >> 3][tid & 7] = Ai[nodeBase * 8 + tid];
    __syncthreads();

    if (tid >= 128) return;
    int ln = tid >> 5, w = tid & 31;
    int n = nodeBase + ln;

    float a[8];
    #pragma unroll
    for (int v = 0; v < 8; ++v) a[v] = sA[ln][v];
    float inv = 1.0f / fmaxf((float)deg[n], 1.0f);

    const float* W0 = tp_w + 0 * 2048;   // path (0,0,0)
    const float* W3 = tp_w + 3 * 2048;   // path (1,0,1)
    const float* W9 = tp_w + 9 * 2048;   // path (2,0,2)

    // l=0 block (32 floats at offset 0)
    {
        float o0 = 0.f;
        #pragma unroll
        for (int u = 0; u < 8; ++u) {
            float c = 0.f;
            #pragma unroll
            for (int v = 0; v < 8; ++v) c += a[v] * W0[(u * 8 + v) * 32 + w];
            o0 += sM[ln][u * 9] * c;
        }
        out[n * 288 + w] = o0 * inv;
    }
    // l=1 block (96 floats at offset 32), layout [w][k], k<3
    {
        float o1[3] = {0.f, 0.f, 0.f};
        #pragma unroll
        for (int u = 0; u < 8; ++u) {
            float c = 0.f;
            #pragma unroll
            for (int v = 0; v < 8; ++v) c += a[v] * W3[(u * 8 + v) * 32 + w];
            #pragma unroll
            for (int k = 0; k < 3; ++k) o1[k] += sM[ln][u * 9 + 1 + k] * c;
        }
        #pragma unroll
        for (int k = 0; k < 3; ++k) out[n * 288 + 32 + w * 3 + k] = o1[k] * inv;
    }
    // l=2 block (160 floats at offset 128), layout [w][k], k<5
    {
        float o2[5] = {0.f, 0.f, 0.f, 0.f, 0.f};
        #pragma unroll
        for (int u = 0; u < 8; ++u) {
            float c = 0.f;
            #pragma unroll
            for (int v = 0; v < 8; ++v) c += a[v] * W9[(u * 8 + v) * 32 + w];
            #pragma unroll
            for (int k = 0; k < 5; ++k) o2[k] += sM[ln][u * 9 + 4 + k] * c;
        }
        #pragma unroll
        for (int k = 0; k < 5; ++k) out[n * 288 + 128 + w * 5 + k] = o2[k] * inv;
    }
}

// ---------------- launch ---------------------------------------------------------
extern "C" void kernel_launch(void* const* d_in, const int* in_sizes, int n_in,
                              void* d_out, int out_size, void* d_ws, size_t ws_size,
                              hipStream_t stream) {
    const float* pos         = (const float*)d_in[0];
    const float* edge_shifts = (const float*)d_in[1];
    const float* cell        = (const float*)d_in[2];
    const float* atom_emb    = (const float*)d_in[3];
    const float* mlp_w1      = (const float*)d_in[4];
    const float* mlp_b1      = (const float*)d_in[5];
    const float* mlp_w2      = (const float*)d_in[6];
    const float* mlp_b2      = (const float*)d_in[7];
    const float* fc_w1       = (const float*)d_in[8];
    const float* fc_b1       = (const float*)d_in[9];
    const float* fc_w2       = (const float*)d_in[10];
    const float* fc_b2       = (const float*)d_in[11];
    const float* fc_w3       = (const float*)d_in[12];
    const float* fc_b3       = (const float*)d_in[13];
    const float* tp_w        = (const float*)d_in[14];
    const int*   A           = (const int*)d_in[15];
    const int*   batch       = (const int*)d_in[16];
    const int*   edge_src    = (const int*)d_in[17];
    const int*   edge_dst    = (const int*)d_in[18];
    float* out = (float*)d_out;

    // workspace layout (all 16B aligned):
    // floats: Q[320000*12] | Ai[80000] | w2T[4096] | w1T[640]
    // ints:   deg[10000] | elist[10000*128]
    float* Q   = (float*)d_ws;
    float* Ai  = Q + (size_t)N_EDGES * 12;
    float* w2T = Ai + N_NODES * 8;
    float* w1T = w2T + 64 * 64;
    int*   deg   = (int*)(w1T + 640);
    int*   elist = deg + N_NODES;
    // total: ~21 MB

    hipMemsetAsync(deg, 0, N_NODES * sizeof(int), stream);

    node_ai_kernel<<<41, 256, 0, stream>>>(
        atom_emb, A, mlp_w1, mlp_b1, mlp_w2, mlp_b2, fc_w1, fc_w2, Ai, w1T, w2T);

    edge_kernel<<<N_EDGES / 256, 256, 0, stream>>>(
        pos, edge_shifts, cell, batch, edge_src, edge_dst,
        w1T, fc_b1, w2T, fc_b2, fc_w3, fc_b3, Q, deg, elist);

    gather_out_kernel<<<N_NODES / 4, 256, 0, stream>>>(
        deg, elist, edge_src, Q, Ai, tp_w, out);
}